// Round 1
// baseline (101.833 us; speedup 1.0000x reference)
//
#include <hip/hip_runtime.h>

#define L_MAX 5
#define D_DIM 32

// Kernel 1: precomp[e*L + l] = dot(edge_vector[l], edge_attr[e])
// E threads, each reads one 128B row via float4 and produces 5 scalars.
__global__ void precompute_dots_kernel(const float* __restrict__ edge_attr,
                                       const float* __restrict__ edge_vector,
                                       float* __restrict__ precomp, int E) {
    __shared__ float ev[L_MAX * D_DIM];
    int tid = threadIdx.x;
    if (tid < L_MAX * D_DIM) ev[tid] = edge_vector[tid];
    __syncthreads();

    int e = blockIdx.x * blockDim.x + tid;
    if (e >= E) return;

    const float4* row = (const float4*)(edge_attr + (size_t)e * D_DIM);
    float acc[L_MAX];
#pragma unroll
    for (int l = 0; l < L_MAX; ++l) acc[l] = 0.f;

#pragma unroll
    for (int c4 = 0; c4 < D_DIM / 4; ++c4) {
        float4 a = row[c4];
#pragma unroll
        for (int l = 0; l < L_MAX; ++l) {
            const float* evl = ev + l * D_DIM + c4 * 4;
            acc[l] += evl[0] * a.x + evl[1] * a.y + evl[2] * a.z + evl[3] * a.w;
        }
    }
#pragma unroll
    for (int l = 0; l < L_MAX; ++l)
        precomp[(size_t)e * L_MAX + l] = acc[l];
}

// Kernel 2: per pair p, masked mean of precomp[path_edges[p][l]*L + l] over l < len.
__global__ void path_mean_kernel(const int* __restrict__ path_edges,
                                 const int* __restrict__ path_len,
                                 const float* __restrict__ precomp,
                                 float* __restrict__ out, int P) {
    int p = blockIdx.x * blockDim.x + threadIdx.x;
    if (p >= P) return;

    int len = path_len[p];
    const int* pe = path_edges + (size_t)p * L_MAX;

    // Load all 5 indices unconditionally (always valid in [0,E)), coalesced 20B/thread.
    int e0 = pe[0], e1 = pe[1], e2 = pe[2], e3 = pe[3], e4 = pe[4];

    float s = 0.f;
    if (0 < len) s += precomp[(size_t)e0 * L_MAX + 0];
    if (1 < len) s += precomp[(size_t)e1 * L_MAX + 1];
    if (2 < len) s += precomp[(size_t)e2 * L_MAX + 2];
    if (3 < len) s += precomp[(size_t)e3 * L_MAX + 3];
    if (4 < len) s += precomp[(size_t)e4 * L_MAX + 4];

    out[p] = (len > 0) ? s / (float)len : 0.f;
}

// Fallback (ws too small): recompute each hop's dot directly from edge_attr.
// Relies on L2/L3 caching of the 16MB edge_attr table.
__global__ void path_mean_direct_kernel(const int* __restrict__ path_edges,
                                        const int* __restrict__ path_len,
                                        const float* __restrict__ edge_attr,
                                        const float* __restrict__ edge_vector,
                                        float* __restrict__ out, int P) {
    __shared__ float ev[L_MAX * D_DIM];
    int tid = threadIdx.x;
    if (tid < L_MAX * D_DIM) ev[tid] = edge_vector[tid];
    __syncthreads();

    int p = blockIdx.x * blockDim.x + tid;
    if (p >= P) return;

    int len = path_len[p];
    const int* pe = path_edges + (size_t)p * L_MAX;

    float s = 0.f;
#pragma unroll
    for (int l = 0; l < L_MAX; ++l) {
        if (l < len) {
            const float4* row = (const float4*)(edge_attr + (size_t)pe[l] * D_DIM);
            float d = 0.f;
#pragma unroll
            for (int c4 = 0; c4 < D_DIM / 4; ++c4) {
                float4 a = row[c4];
                const float* evl = ev + l * D_DIM + c4 * 4;
                d += evl[0] * a.x + evl[1] * a.y + evl[2] * a.z + evl[3] * a.w;
            }
            s += d;
        }
    }
    out[p] = (len > 0) ? s / (float)len : 0.f;
}

extern "C" void kernel_launch(void* const* d_in, const int* in_sizes, int n_in,
                              void* d_out, int out_size, void* d_ws, size_t ws_size,
                              hipStream_t stream) {
    // Inputs (setup_inputs order): x [N*D], edge_attr [E*D], edge_vector [L*D],
    // path_edges [P*L] int32, path_len [P] int32. x is UNUSED by the reference.
    const float* edge_attr   = (const float*)d_in[1];
    const float* edge_vector = (const float*)d_in[2];
    const int*   path_edges  = (const int*)d_in[3];
    const int*   path_len    = (const int*)d_in[4];
    float* out = (float*)d_out;

    const int E = in_sizes[1] / D_DIM;
    const int P = in_sizes[4];

    const size_t precomp_bytes = (size_t)E * L_MAX * sizeof(float);

    if (ws_size >= precomp_bytes) {
        float* precomp = (float*)d_ws;
        {
            int block = 256;
            int grid = (E + block - 1) / block;
            precompute_dots_kernel<<<grid, block, 0, stream>>>(edge_attr, edge_vector,
                                                               precomp, E);
        }
        {
            int block = 256;
            int grid = (P + block - 1) / block;
            path_mean_kernel<<<grid, block, 0, stream>>>(path_edges, path_len,
                                                         precomp, out, P);
        }
    } else {
        int block = 256;
        int grid = (P + block - 1) / block;
        path_mean_direct_kernel<<<grid, block, 0, stream>>>(path_edges, path_len,
                                                            edge_attr, edge_vector,
                                                            out, P);
    }
}